// Round 3
// baseline (1120.320 us; speedup 1.0000x reference)
//
#include <hip/hip_runtime.h>

#define N_NODES 100000
#define N_EDGES 1600000
#define D_IN    128
#define D_OUT   256
#define NB_SCAN ((N_NODES + 255) / 256)   // 391 blocks for node-indexed scans
#define BLK_ROWS 32                       // 100000 / 32 = 3125 blocks, exact

// ---------------------------------------------------------------------------
// Detect whether edge_index was materialized as int64 or int32.
// Values are in [0, 100000). If int64 (LE), every odd int32 word is zero.
// ---------------------------------------------------------------------------
__global__ void detect_idx64_kernel(const int* __restrict__ edge32,
                                    int* __restrict__ flag) {
    if (threadIdx.x == 0 && blockIdx.x == 0) {
        int is64 = 1;
        for (int i = 1; i < 32; i += 2) {
            if (edge32[i] != 0) { is64 = 0; break; }
        }
        *flag = is64;
    }
}

__device__ __forceinline__ int load_dst(const void* edge_raw, int is64, int e) {
    if (is64) return (int)((const long long*)edge_raw)[(long long)N_EDGES + e];
    return ((const int*)edge_raw)[N_EDGES + e];
}
__device__ __forceinline__ int load_src(const void* edge_raw, int is64, int e) {
    if (is64) return (int)((const long long*)edge_raw)[e];
    return ((const int*)edge_raw)[e];
}

// ---------------------------------------------------------------------------
// 1) histogram of destinations into counts[]
// ---------------------------------------------------------------------------
__global__ __launch_bounds__(256) void hist_kernel(
        const void* __restrict__ edge_raw, const int* __restrict__ flag,
        int* __restrict__ counts) {
    int e = blockIdx.x * blockDim.x + threadIdx.x;
    if (e >= N_EDGES) return;
    int dst = load_dst(edge_raw, *flag, e);
    if ((unsigned)dst < N_NODES) atomicAdd(&counts[dst], 1);
}

// ---------------------------------------------------------------------------
// 2a) per-256-block sums of counts -> bsum[NB_SCAN]
// ---------------------------------------------------------------------------
__global__ __launch_bounds__(256) void block_sum_kernel(
        const int* __restrict__ counts, int* __restrict__ bsum) {
    __shared__ int lds[256];
    int t = threadIdx.x;
    int i = blockIdx.x * 256 + t;
    lds[t] = (i < N_NODES) ? counts[i] : 0;
    __syncthreads();
    for (int off = 128; off > 0; off >>= 1) {
        if (t < off) lds[t] += lds[t + off];
        __syncthreads();
    }
    if (t == 0) bsum[blockIdx.x] = lds[0];
}

// ---------------------------------------------------------------------------
// 2b) exclusive scan of bsum (391 elems) in one 512-thread block.
// ---------------------------------------------------------------------------
__global__ __launch_bounds__(512) void scan_bsum_kernel(
        int* __restrict__ bsum, int* __restrict__ row_start) {
    __shared__ int lds[512];
    int t = threadIdx.x;
    lds[t] = (t < NB_SCAN) ? bsum[t] : 0;
    __syncthreads();
    for (int off = 1; off < 512; off <<= 1) {
        int u = (t >= off) ? lds[t - off] : 0;
        __syncthreads();
        lds[t] += u;
        __syncthreads();
    }
    int excl = (t == 0) ? 0 : lds[t - 1];
    if (t < NB_SCAN) bsum[t] = excl;
    if (t == 0) row_start[N_NODES] = N_EDGES;
}

// ---------------------------------------------------------------------------
// 2c) per-element exclusive scan: row_start + cursor init
// ---------------------------------------------------------------------------
__global__ __launch_bounds__(256) void scan_counts_kernel(
        int* __restrict__ counts_cursor, const int* __restrict__ bsum,
        int* __restrict__ row_start) {
    __shared__ int lds[256];
    int t = threadIdx.x;
    int i = blockIdx.x * 256 + t;
    int c = (i < N_NODES) ? counts_cursor[i] : 0;
    lds[t] = c;
    __syncthreads();
    for (int off = 1; off < 256; off <<= 1) {
        int u = (t >= off) ? lds[t - off] : 0;
        __syncthreads();
        lds[t] += u;
        __syncthreads();
    }
    int rs = bsum[blockIdx.x] + lds[t] - c;   // exclusive
    if (i < N_NODES) {
        row_start[i] = rs;
        counts_cursor[i] = rs;                // cursor starts at row_start
    }
}

// ---------------------------------------------------------------------------
// 3) fill CSR: csr_src[pos] = src, pos = cursor[dst]++
// ---------------------------------------------------------------------------
__global__ __launch_bounds__(256) void fill_kernel(
        const void* __restrict__ edge_raw, const int* __restrict__ flag,
        int* __restrict__ cursor, int* __restrict__ csr_src) {
    int e = blockIdx.x * blockDim.x + threadIdx.x;
    if (e >= N_EDGES) return;
    int is64 = *flag;
    int src = load_src(edge_raw, is64, e);
    int dst = load_dst(edge_raw, is64, e);
    if ((unsigned)dst >= N_NODES || (unsigned)src >= N_NODES) return;
    int pos = atomicAdd(&cursor[dst], 1);
    csr_src[pos] = src;
}

// ---------------------------------------------------------------------------
// 4) fused gather + GEMM + ReLU.
//    32 rows x 256 cols per 256-thread block (4 waves, 8 rows/wave).
//    Gather: per-wave LDS index buffer (coalesced csr read, ds_read
//    broadcast), 8 neighbor rows in flight (explicit regs, no arrays).
//    GEMM: per-thread 8 rows x 4 cols, f32 vector FMA.
//    __launch_bounds__(256,8): VGPR<=64 -> 8 blocks/CU (LDS 17KB) -> 32 w/CU.
// ---------------------------------------------------------------------------
__global__ __launch_bounds__(256, 8) void gather_gemm_relu_kernel(
        const float* __restrict__ H,
        const int* __restrict__ row_start,
        const int* __restrict__ csr_src,
        const float* __restrict__ Wm,
        float* __restrict__ out) {
    __shared__ float Xs[BLK_ROWS][D_IN];
    __shared__ int idx_lds[4][64];

    const int g    = blockIdx.x * BLK_ROWS;   // grid exact: no row guards
    const int tid  = threadIdx.x;
    const int wv   = tid >> 6;
    const int lane = tid & 63;

    // ---- gather phase: wave wv produces rows wv*8 .. wv*8+7 ----
    #pragma unroll 1
    for (int jj = 0; jj < 8; ++jj) {
        const int r   = wv * 8 + jj;
        const int row = g + r;

        float2 s = ((const float2*)(H + (size_t)row * D_IN))[lane];
        const int start = row_start[row];
        const int end   = row_start[row + 1];

        for (int base = start; base < end; base += 64) {
            int m = end - base;
            if (m > 64) m = 64;
            if (lane < m) idx_lds[wv][lane] = csr_src[base + lane];
            // wave-local LDS RAW: DS ops complete in order per wave;
            // compiler inserts lgkmcnt waits.
            int n = 0;
            for (; n + 8 <= m; n += 8) {
                const int i0 = idx_lds[wv][n + 0];
                const int i1 = idx_lds[wv][n + 1];
                const int i2 = idx_lds[wv][n + 2];
                const int i3 = idx_lds[wv][n + 3];
                const int i4 = idx_lds[wv][n + 4];
                const int i5 = idx_lds[wv][n + 5];
                const int i6 = idx_lds[wv][n + 6];
                const int i7 = idx_lds[wv][n + 7];
                const float2 v0 = ((const float2*)(H + (size_t)i0 * D_IN))[lane];
                const float2 v1 = ((const float2*)(H + (size_t)i1 * D_IN))[lane];
                const float2 v2 = ((const float2*)(H + (size_t)i2 * D_IN))[lane];
                const float2 v3 = ((const float2*)(H + (size_t)i3 * D_IN))[lane];
                const float2 v4 = ((const float2*)(H + (size_t)i4 * D_IN))[lane];
                const float2 v5 = ((const float2*)(H + (size_t)i5 * D_IN))[lane];
                const float2 v6 = ((const float2*)(H + (size_t)i6 * D_IN))[lane];
                const float2 v7 = ((const float2*)(H + (size_t)i7 * D_IN))[lane];
                s.x += v0.x; s.y += v0.y;
                s.x += v1.x; s.y += v1.y;
                s.x += v2.x; s.y += v2.y;
                s.x += v3.x; s.y += v3.y;
                s.x += v4.x; s.y += v4.y;
                s.x += v5.x; s.y += v5.y;
                s.x += v6.x; s.y += v6.y;
                s.x += v7.x; s.y += v7.y;
            }
            for (; n < m; ++n) {
                const int i0 = idx_lds[wv][n];
                const float2 v = ((const float2*)(H + (size_t)i0 * D_IN))[lane];
                s.x += v.x; s.y += v.y;
            }
        }
        ((float2*)&Xs[r][0])[lane] = s;
    }
    __syncthreads();

    // ---- GEMM + ReLU: wave wv -> rows wv*8..+7, lane -> cols lane*4..+3 ----
    float acc0[4], acc1[4], acc2[4], acc3[4], acc4[4], acc5[4], acc6[4], acc7[4];
    #pragma unroll
    for (int j = 0; j < 4; ++j) {
        acc0[j] = 0.f; acc1[j] = 0.f; acc2[j] = 0.f; acc3[j] = 0.f;
        acc4[j] = 0.f; acc5[j] = 0.f; acc6[j] = 0.f; acc7[j] = 0.f;
    }

    const float* Wp = Wm + lane * 4;

    #pragma unroll 1
    for (int k = 0; k < D_IN; k += 4) {
        const float4 w0 = *reinterpret_cast<const float4*>(Wp + (k + 0) * D_OUT);
        const float4 w1 = *reinterpret_cast<const float4*>(Wp + (k + 1) * D_OUT);
        const float4 w2 = *reinterpret_cast<const float4*>(Wp + (k + 2) * D_OUT);
        const float4 w3 = *reinterpret_cast<const float4*>(Wp + (k + 3) * D_OUT);
#define ROW_FMA(ACC, RR)                                                      \
        {                                                                     \
            const float4 x = *reinterpret_cast<const float4*>(                \
                &Xs[wv * 8 + (RR)][k]);                                       \
            ACC[0] = fmaf(x.x, w0.x, ACC[0]); ACC[0] = fmaf(x.y, w1.x, ACC[0]);\
            ACC[0] = fmaf(x.z, w2.x, ACC[0]); ACC[0] = fmaf(x.w, w3.x, ACC[0]);\
            ACC[1] = fmaf(x.x, w0.y, ACC[1]); ACC[1] = fmaf(x.y, w1.y, ACC[1]);\
            ACC[1] = fmaf(x.z, w2.y, ACC[1]); ACC[1] = fmaf(x.w, w3.y, ACC[1]);\
            ACC[2] = fmaf(x.x, w0.z, ACC[2]); ACC[2] = fmaf(x.y, w1.z, ACC[2]);\
            ACC[2] = fmaf(x.z, w2.z, ACC[2]); ACC[2] = fmaf(x.w, w3.z, ACC[2]);\
            ACC[3] = fmaf(x.x, w0.w, ACC[3]); ACC[3] = fmaf(x.y, w1.w, ACC[3]);\
            ACC[3] = fmaf(x.z, w2.w, ACC[3]); ACC[3] = fmaf(x.w, w3.w, ACC[3]);\
        }
        ROW_FMA(acc0, 0) ROW_FMA(acc1, 1) ROW_FMA(acc2, 2) ROW_FMA(acc3, 3)
        ROW_FMA(acc4, 4) ROW_FMA(acc5, 5) ROW_FMA(acc6, 6) ROW_FMA(acc7, 7)
#undef ROW_FMA
    }

#define ROW_STORE(ACC, RR)                                                    \
    {                                                                         \
        const int row = g + wv * 8 + (RR);                                    \
        float4 o;                                                             \
        o.x = fmaxf(ACC[0], 0.f); o.y = fmaxf(ACC[1], 0.f);                   \
        o.z = fmaxf(ACC[2], 0.f); o.w = fmaxf(ACC[3], 0.f);                   \
        *reinterpret_cast<float4*>(out + (size_t)row * D_OUT + lane * 4) = o; \
    }
    ROW_STORE(acc0, 0) ROW_STORE(acc1, 1) ROW_STORE(acc2, 2) ROW_STORE(acc3, 3)
    ROW_STORE(acc4, 4) ROW_STORE(acc5, 5) ROW_STORE(acc6, 6) ROW_STORE(acc7, 7)
#undef ROW_STORE
}

extern "C" void kernel_launch(void* const* d_in, const int* in_sizes, int n_in,
                              void* d_out, int out_size, void* d_ws, size_t ws_size,
                              hipStream_t stream) {
    const float* H    = (const float*)d_in[0];
    const void*  edge = d_in[1];
    const float* Wm   = (const float*)d_in[2];
    float* out = (float*)d_out;

    // workspace layout (16B-aligned)
    const size_t off_rs   = 0;                                              // (N+1) ints
    const size_t off_cur  = ((size_t)(N_NODES + 1) * 4 + 15) & ~(size_t)15;
    const size_t off_csr  = off_cur + (size_t)N_NODES * 4;
    const size_t off_bsum = off_csr + (size_t)N_EDGES * 4;
    const size_t off_flag = off_bsum + (((size_t)NB_SCAN * 4 + 15) & ~(size_t)15);

    int* row_start = (int*)((char*)d_ws + off_rs);
    int* cursor    = (int*)((char*)d_ws + off_cur);   // doubles as counts
    int* csr_src   = (int*)((char*)d_ws + off_csr);
    int* bsum      = (int*)((char*)d_ws + off_bsum);
    int* flag      = (int*)((char*)d_ws + off_flag);

    detect_idx64_kernel<<<1, 64, 0, stream>>>((const int*)edge, flag);

    hipMemsetAsync(cursor, 0, (size_t)N_NODES * 4, stream);

    const int edge_blocks = (N_EDGES + 255) / 256;
    hist_kernel<<<edge_blocks, 256, 0, stream>>>(edge, flag, cursor);
    block_sum_kernel<<<NB_SCAN, 256, 0, stream>>>(cursor, bsum);
    scan_bsum_kernel<<<1, 512, 0, stream>>>(bsum, row_start);
    scan_counts_kernel<<<NB_SCAN, 256, 0, stream>>>(cursor, bsum, row_start);
    fill_kernel<<<edge_blocks, 256, 0, stream>>>(edge, flag, cursor, csr_src);

    const int gemm_blocks = N_NODES / BLK_ROWS;   // 3125, exact
    gather_gemm_relu_kernel<<<gemm_blocks, 256, 0, stream>>>(
        H, row_start, csr_src, Wm, out);
}